// Round 1
// baseline (66.017 us; speedup 1.0000x reference)
//
#include <hip/hip_runtime.h>

#define H 256
#define W 256
#define C 3
#define NUM 2048
#define PS 25   // kernel_size_search
#define KS 9    // kernel_size_center
#define SP 12   // PS/2
#define PAD 16  // KS/2 + SP
#define WIN 33  // KS + PS - 1
#define WROW 36 // padded LDS row stride (multiple of 4 -> 16B-aligned rows)
#define WCH (WIN*WROW)
#define WTOT (C*WCH)

__global__ __launch_bounds__(64) void simmap_kernel(
    const float* __restrict__ img, const float* __restrict__ img_sr,
    const float* __restrict__ sigma, const int* __restrict__ coords,
    float* __restrict__ out)
{
    __shared__ __align__(16) float win[WTOT];
    const int n = blockIdx.x;
    const int imgid = blockIdx.y;
    const float* im = imgid ? img_sr : img;
    const int t = threadIdx.x;
    const int r0 = coords[2*n];
    const int c0 = coords[2*n+1];

    // stage 3x33x33 window (zero-padded borders) into LDS
    for (int f = t; f < C*WIN*WIN; f += 64) {
        int c  = f / (WIN*WIN);
        int rem = f - c*(WIN*WIN);
        int wr = rem / WIN;
        int wc = rem - wr*WIN;
        int ri = r0 + wr - PAD;
        int ci = c0 + wc - PAD;
        float v = 0.f;
        if (ri >= 0 && ri < H && ci >= 0 && ci < W)
            v = im[c*(H*W) + ri*W + ci];
        win[c*WCH + wr*WROW + wc] = v;
    }
    __syncthreads();

    if (t >= 50) return;

    const int d0  = t >> 1;          // 0..24 row shift
    const int d1b = (t & 1) * 12;    // 0 or 12 (16B-aligned col base)

    float acc[13];
    #pragma unroll
    for (int o = 0; o < 13; ++o) acc[o] = 0.f;

    for (int c = 0; c < C; ++c) {
        for (int i = 0; i < KS; ++i) {
            // center row: broadcast (same address all lanes), 16B-aligned
            const float* crow = &win[c*WCH + (SP + i)*WROW + SP];
            float4 cv0 = *(const float4*)(crow);
            float4 cv1 = *(const float4*)(crow + 4);
            float cr[9];
            cr[0]=cv0.x; cr[1]=cv0.y; cr[2]=cv0.z; cr[3]=cv0.w;
            cr[4]=cv1.x; cr[5]=cv1.y; cr[6]=cv1.z; cr[7]=cv1.w;
            cr[8]=crow[8];
            // shifted row segment: floats [d1b .. d1b+23], 16B-aligned
            const float* rrow = &win[c*WCH + (i + d0)*WROW + d1b];
            float rv[24];
            #pragma unroll
            for (int q = 0; q < 6; ++q) {
                float4 v = *(const float4*)(rrow + 4*q);
                rv[4*q+0]=v.x; rv[4*q+1]=v.y; rv[4*q+2]=v.z; rv[4*q+3]=v.w;
            }
            #pragma unroll
            for (int j = 0; j < KS; ++j) {
                #pragma unroll
                for (int o = 0; o < 13; ++o) {
                    float d = rv[o + j] - cr[j];
                    acc[o] += d * d;
                }
            }
        }
    }

    float s = sigma[0];
    s = fmaxf(s, 0.f);
    const float scale = -1.f / (243.f * s);
    float* op = out + ((size_t)imgid * NUM + n) * 625 + d0 * 25 + d1b;
    #pragma unroll
    for (int o = 0; o < 13; ++o)
        op[o] = __expf(acc[o] * scale + 1e-20f);
}

extern "C" void kernel_launch(void* const* d_in, const int* in_sizes, int n_in,
                              void* d_out, int out_size, void* d_ws, size_t ws_size,
                              hipStream_t stream) {
    const float* img    = (const float*)d_in[0];
    const float* img_sr = (const float*)d_in[1];
    const float* sigma  = (const float*)d_in[2];
    const int*   coords = (const int*)d_in[3];
    float* out = (float*)d_out;
    dim3 grid(NUM, 2);
    simmap_kernel<<<grid, dim3(64), 0, stream>>>(img, img_sr, sigma, coords, out);
}

// Round 2
// 48.372 us; speedup vs baseline: 1.3648x; 1.3648x over previous
//
#include <hip/hip_runtime.h>

#define H 256
#define W 256
#define C 3
#define NUM 2048
#define PS 25   // kernel_size_search
#define KS 9    // kernel_size_center
#define SP 12   // PS/2
#define PAD 16  // KS/2 + SP
#define WIN 33  // KS + PS - 1
#define WROW 36 // padded LDS row stride (mult of 4 -> 16B-aligned b128)
#define WCH (WIN*WROW)
#define HROW 28 // hs row stride (mult of 4, 7r mod 8 spreads banks)

__global__ __launch_bounds__(64) void simmap_kernel(
    const float* __restrict__ img, const float* __restrict__ img_sr,
    const float* __restrict__ sigma, const int* __restrict__ coords,
    float* __restrict__ out)
{
    __shared__ __align__(16) float win[C*WCH];
    __shared__ __align__(16) float hs[WIN*HROW];
    const int n = blockIdx.x;
    const int imgid = blockIdx.y;
    const float* im = imgid ? img_sr : img;
    const int t = threadIdx.x;
    const int r0 = coords[2*n];
    const int c0 = coords[2*n+1];

    // ---- stage 3x33x33 window (zero-padded) into LDS ----
    if (r0 >= PAD && r0 < H-PAD && c0 >= PAD && c0 < W-PAD) {
        // interior fast path: no per-element bounds checks
        const float* base = im + (r0-PAD)*W + (c0-PAD);
        for (int f = t; f < C*WIN*WIN; f += 64) {
            int c  = f / (WIN*WIN);
            int rem = f - c*(WIN*WIN);
            int wr = rem / WIN;
            int wc = rem - wr*WIN;
            win[c*WCH + wr*WROW + wc] = base[c*(H*W) + wr*W + wc];
        }
    } else {
        for (int f = t; f < C*WIN*WIN; f += 64) {
            int c  = f / (WIN*WIN);
            int rem = f - c*(WIN*WIN);
            int wr = rem / WIN;
            int wc = rem - wr*WIN;
            int ri = r0 + wr - PAD;
            int ci = c0 + wc - PAD;
            float v = 0.f;
            if (ri >= 0 && ri < H && ci >= 0 && ci < W)
                v = im[c*(H*W) + ri*W + ci];
            win[c*WCH + wr*WROW + wc] = v;
        }
    }
    __syncthreads();

    // ---- phase 2a: horizontal sliding sums of squares, summed over channels
    // hs[r][d1] = sum_c sum_{j=0..8} win[c][r][d1+j]^2
    if (t < WIN) {
        float hsv[PS];
        #pragma unroll
        for (int d = 0; d < PS; ++d) hsv[d] = 0.f;
        #pragma unroll 1
        for (int c = 0; c < C; ++c) {
            const float* row = &win[c*WCH + t*WROW];
            float sq[WIN];
            #pragma unroll
            for (int q = 0; q < 8; ++q) {
                float4 v = *(const float4*)(row + 4*q);
                sq[4*q+0]=v.x*v.x; sq[4*q+1]=v.y*v.y;
                sq[4*q+2]=v.z*v.z; sq[4*q+3]=v.w*v.w;
            }
            { float v = row[32]; sq[32] = v*v; }
            float s = 0.f;
            #pragma unroll
            for (int j = 0; j < KS; ++j) s += sq[j];
            hsv[0] += s;
            #pragma unroll
            for (int d = 1; d < PS; ++d) {
                s += sq[d+KS-1] - sq[d-1];
                hsv[d] += s;
            }
        }
        #pragma unroll
        for (int d = 0; d < PS; ++d) hs[t*HROW + d] = hsv[d];
    }
    __syncthreads();

    if (t >= 50) return;

    const int d0  = t >> 1;        // 0..24 row shift
    const int d1b = (t & 1) * 12;  // 0 or 12 (16B-aligned col base)

    // ---- cross-correlation term: cr[o] = sum s*c ----
    float cr[13];
    #pragma unroll
    for (int o = 0; o < 13; ++o) cr[o] = 0.f;

    #pragma unroll 1
    for (int c = 0; c < C; ++c) {
        const float* chan = &win[c*WCH];
        #pragma unroll
        for (int i = 0; i < KS; ++i) {
            const float* crow = chan + (SP + i)*WROW + SP;   // broadcast
            float4 cv0 = *(const float4*)(crow);
            float4 cv1 = *(const float4*)(crow + 4);
            float cw[9] = {cv0.x,cv0.y,cv0.z,cv0.w,cv1.x,cv1.y,cv1.z,cv1.w,crow[8]};
            const float* rrow = chan + (i + d0)*WROW + d1b;
            float rv[24];
            #pragma unroll
            for (int q = 0; q < 6; ++q) {
                float4 v = *(const float4*)(rrow + 4*q);
                rv[4*q+0]=v.x; rv[4*q+1]=v.y; rv[4*q+2]=v.z; rv[4*q+3]=v.w;
            }
            #pragma unroll
            for (int j = 0; j < KS; ++j) {
                #pragma unroll
                for (int o = 0; o < 13; ++o)
                    cr[o] = fmaf(rv[o + j], cw[j], cr[o]);
            }
        }
    }

    // ---- box sum of squares via vertical sum of hs ----
    float bs[13];
    #pragma unroll
    for (int o = 0; o < 13; ++o) bs[o] = 0.f;
    #pragma unroll
    for (int i = 0; i < KS; ++i) {
        const float* hr = &hs[(d0 + i)*HROW + d1b];
        float4 a = *(const float4*)(hr);
        float4 b = *(const float4*)(hr + 4);
        float4 d = *(const float4*)(hr + 8);
        float hv[13] = {a.x,a.y,a.z,a.w,b.x,b.y,b.z,b.w,d.x,d.y,d.z,d.w,hr[12]};
        #pragma unroll
        for (int o = 0; o < 13; ++o) bs[o] += hv[o];
    }

    // center-patch energy: cc = BS[12][12] (broadcast reads)
    float cc = 0.f;
    #pragma unroll
    for (int i = 0; i < KS; ++i) cc += hs[(SP + i)*HROW + SP];

    float s = fmaxf(sigma[0], 0.f);
    const float scale = -1.f / (243.f * s);
    float* op = out + ((size_t)imgid * NUM + n) * 625 + d0 * 25 + d1b;
    #pragma unroll
    for (int o = 0; o < 13; ++o) {
        float ssd = bs[o] + cc - 2.f * cr[o];
        op[o] = __expf(ssd * scale + 1e-20f);
    }
}

extern "C" void kernel_launch(void* const* d_in, const int* in_sizes, int n_in,
                              void* d_out, int out_size, void* d_ws, size_t ws_size,
                              hipStream_t stream) {
    const float* img    = (const float*)d_in[0];
    const float* img_sr = (const float*)d_in[1];
    const float* sigma  = (const float*)d_in[2];
    const int*   coords = (const int*)d_in[3];
    float* out = (float*)d_out;
    dim3 grid(NUM, 2);
    simmap_kernel<<<grid, dim3(64), 0, stream>>>(img, img_sr, sigma, coords, out);
}